// Round 9
// baseline (64.488 us; speedup 1.0000x reference)
//
#include <hip/hip_runtime.h>
#include <math.h>

#define B_  4
#define S_  2048
#define H_  16
#define DK_ 8
#define E_  128

typedef _Float16 f16x8  __attribute__((ext_vector_type(8)));
typedef __fp16   h2     __attribute__((ext_vector_type(2)));
typedef float    f32x16 __attribute__((ext_vector_type(16)));
typedef int      i32x2  __attribute__((ext_vector_type(2)));

union U4  { unsigned u[4]; f16x8 v; uint4 q; };
union H2U { h2 h; unsigned u; };

// log2(e)/sqrt(8): folds the 1/sqrt(dk) softmax scale and the exp->exp2 conversion
#define KSC 0.51006972f

static __device__ __forceinline__ float frcp(float x) {
#if __has_builtin(__builtin_amdgcn_rcpf)
    return __builtin_amdgcn_rcpf(x);
#else
    return 1.0f / x;
#endif
}

// Packed exp2 of a score pair, NO transcendental ops: cvt to f16 pair, magic
// round (ulp=1 at 1536 -> RNE integer), exact frac, cubic poly (rel err ~8e-4),
// then scale by 2^j via exponent-field bit add. |x| <= 4.6 required (ours: 4.1).
static __device__ __forceinline__ unsigned pkexp2(float lo, float hi) {
    H2U x;  x.h = __builtin_amdgcn_cvt_pkrtz(lo, hi);
    h2 t = x.h + (__fp16)1536.0f;                 // round(x) + 1536 (RNE)
    h2 r = t - (__fp16)1536.0f;                   // round(x)
    h2 f = x.h - r;                               // frac in [-0.5, 0.5], exact
    h2 p = f * (__fp16)0.0554906f + (__fp16)0.2401597f;
    p = f * p + (__fp16)0.6931472f;
    p = f * p + (__fp16)1.0f;                     // ~2^f
    H2U tu; tu.h = t;
    H2U pu; pu.h = p;
    unsigned sh = (tu.u << 10) & 0xFC00FC00u;     // (j<<10) mod 2^16, per half
    unsigned res;
    asm("v_pk_add_u16 %0, %1, %2" : "=v"(res) : "v"(pu.u), "v"(sh));
    return res;                                    // f16 pair: 2^x
}

// ---------------------------------------------------------------------------
// Fused quantum projection + attention, MFMA path, key-split waves.
// Block = 1024 thr (16 waves) = 8 q-groups x 2 key-halves; one (b,h) slice
// per blockIdx.y, 256 q-rows per block; LDS-merge of the two key-half
// partials (additive, no max bookkeeping). Round-9 change: the 16 v_exp_f32
// per tile are replaced by 8 packed-f16 polynomial exp2's (full-rate pipe) --
// tests the hypothesis that the trans pipe was the invariant ~43us wall that
// TLP/ILP/stagger (r5/r7/r8) could not move.
// ---------------------------------------------------------------------------
__global__ __launch_bounds__(1024, 8)
void qattn_mfma(const float* __restrict__ x, const float* __restrict__ theta,
                float* __restrict__ out) {
    constexpr int VST = 2056;                       // V^T row stride (bank-spread, 16B aligned)
    __shared__ __align__(16) _Float16 smem[S_ * DK_ + 9 * VST];
    _Float16* Klds = smem;                          // [2048][8]
    _Float16* Vt   = smem + S_ * DK_;               // [9][VST]

    const int tid  = threadIdx.x;
    const int lane = tid & 63;
    const int wv   = tid >> 6;                      // 0..15
    const int bh   = blockIdx.y;
    const int b    = bh >> 4;
    const int h    = bh & 15;

    // ---- stage cos(x+theta): K row-major + V^T (one key-pair per thread) ----
    {
        float th[DK_];
#pragma unroll
        for (int d = 0; d < DK_; ++d) th[d] = theta[d];

        const float* xp = x + ((size_t)b * S_) * E_ + h * DK_;
        const int s0 = tid * 2;
        float4 a0 = *(const float4*)(xp + (size_t)s0 * E_);
        float4 a1 = *(const float4*)(xp + (size_t)s0 * E_ + 4);
        float4 b0 = *(const float4*)(xp + (size_t)(s0 + 1) * E_);
        float4 b1 = *(const float4*)(xp + (size_t)(s0 + 1) * E_ + 4);
        float ca[8], cb[8];
        ca[0]=__cosf(a0.x+th[0]); ca[1]=__cosf(a0.y+th[1]); ca[2]=__cosf(a0.z+th[2]); ca[3]=__cosf(a0.w+th[3]);
        ca[4]=__cosf(a1.x+th[4]); ca[5]=__cosf(a1.y+th[5]); ca[6]=__cosf(a1.z+th[6]); ca[7]=__cosf(a1.w+th[7]);
        cb[0]=__cosf(b0.x+th[0]); cb[1]=__cosf(b0.y+th[1]); cb[2]=__cosf(b0.z+th[2]); cb[3]=__cosf(b0.w+th[3]);
        cb[4]=__cosf(b1.x+th[4]); cb[5]=__cosf(b1.y+th[5]); cb[6]=__cosf(b1.z+th[6]); cb[7]=__cosf(b1.w+th[7]);

        H2U p0, p1, p2, p3;
        p0.h = __builtin_amdgcn_cvt_pkrtz(ca[0], ca[1]);
        p1.h = __builtin_amdgcn_cvt_pkrtz(ca[2], ca[3]);
        p2.h = __builtin_amdgcn_cvt_pkrtz(ca[4], ca[5]);
        p3.h = __builtin_amdgcn_cvt_pkrtz(ca[6], ca[7]);
        *(uint4*)&Klds[(size_t)s0 * DK_] = make_uint4(p0.u, p1.u, p2.u, p3.u);
        p0.h = __builtin_amdgcn_cvt_pkrtz(cb[0], cb[1]);
        p1.h = __builtin_amdgcn_cvt_pkrtz(cb[2], cb[3]);
        p2.h = __builtin_amdgcn_cvt_pkrtz(cb[4], cb[5]);
        p3.h = __builtin_amdgcn_cvt_pkrtz(cb[6], cb[7]);
        *(uint4*)&Klds[(size_t)(s0 + 1) * DK_] = make_uint4(p0.u, p1.u, p2.u, p3.u);

#pragma unroll
        for (int d = 0; d < DK_; ++d) {             // V^T: (key s0, s0+1) pair
            H2U tv; tv.h = __builtin_amdgcn_cvt_pkrtz(ca[d], cb[d]);
            *(unsigned*)&Vt[d * VST + s0] = tv.u;
        }
        *(unsigned*)&Vt[8 * VST + s0] = 0x3C003C00u;  // ones row -> denominator
    }
    __syncthreads();

    // ---- wave = (q-group, key-half) ----
    const int  qg    = wv & 7;
    const int  kh    = wv >> 3;
    const int  qrow0 = blockIdx.x * 256 + qg * 32;
    const int  t0    = kh * 32;                     // this wave's first key-tile
    const int  l31   = lane & 31;
    const int  hi    = lane >> 5;
    const bool lo32  = (lane < 32);

    f16x8 qf = {};                                  // Q^T B-frag: lanes>=32 zero (dims 8..15)
    if (lo32) {
        qf = *(const f16x8*)&Klds[(size_t)(qrow0 + l31) * DK_];
#pragma unroll
        for (int d = 0; d < DK_; ++d)               // fold softmax scale + log2e into Q
            qf[d] = qf[d] * (_Float16)KSC;
    }

    const f32x16 z16 = {};                          // constant zero C operand
    f32x16 accO = {};                               // O accumulator (col = lane&31)

    const int nc = (l31 <= 8) ? l31 : 8;            // clamp unused cols to ones row
    const _Float16* vbase = &Vt[nc * VST + hi * 8];

    // kf loads are unconditional: lanes>=32 duplicate their l31 partner's row;
    // their A-contribution hits qf's zeroed k=8..15 half -> 0.
    for (int kt = t0; kt < t0 + 32; ++kt) {
        f16x8 kf = *(const f16x8*)&Klds[(size_t)(kt * 32 + l31) * DK_];
        // S^T[key][qrow] for 32 keys x 32 qrows; lane holds 16 keys of qrow=lane&31
        f32x16 sc = __builtin_amdgcn_mfma_f32_32x32x16_f16(kf, qf, z16, 0, 0, 0);

        unsigned X[4][2];                           // X[q] = f16 pair-packed exp(scores)
#pragma unroll
        for (int q = 0; q < 4; ++q) {
            X[q][0] = pkexp2(sc[4 * q + 0], sc[4 * q + 1]);
            X[q][1] = pkexp2(sc[4 * q + 2], sc[4 * q + 3]);
        }

#pragma unroll
        for (int s = 0; s < 2; ++s) {               // two PV steps of 16 keys
            U4 pa;
#pragma unroll
            for (int i = 0; i < 2; ++i) {
                i32x2 r = __builtin_amdgcn_permlane32_swap(
                    (int)X[2 * s][i], (int)X[2 * s + 1][i], false, false);
                pa.u[i]     = (unsigned)r[0];       // keys j=0..3 (from hi=0 half)
                pa.u[2 + i] = (unsigned)r[1];       // keys j=4..7 (from hi=1 half)
            }
            f16x8 vf = *(const f16x8*)(vbase + kt * 32 + s * 16);
            accO = __builtin_amdgcn_mfma_f32_32x32x16_f16(pa.v, vf, accO, 0, 0, 0);
        }
    }

    // ---- merge key-halves: kh=1 waves dump accO to LDS, kh=0 waves add ----
    __syncthreads();                                // all LDS reads done
    float* scratch = (float*)smem;                  // reuse Klds region, 32KB
    if (kh == 1) {
        float4* dst = (float4*)&scratch[(size_t)(qg * 64 + lane) * 16];
#pragma unroll
        for (int i = 0; i < 4; ++i)
            dst[i] = make_float4(accO[4*i], accO[4*i+1], accO[4*i+2], accO[4*i+3]);
    }
    __syncthreads();
    if (kh == 0) {
        const float4* src = (const float4*)&scratch[(size_t)(qg * 64 + lane) * 16];
#pragma unroll
        for (int i = 0; i < 4; ++i) {
            float4 p = src[i];
            accO[4*i+0] += p.x; accO[4*i+1] += p.y;
            accO[4*i+2] += p.z; accO[4*i+3] += p.w;
        }

        // ---- epilogue: normalize by col-8 (ones column) and store ----
        const int n = l31;
        float* obase = out + ((size_t)(b * S_ + qrow0)) * E_ + h * DK_ + n;
#pragma unroll
        for (int i = 0; i < 16; ++i) {
            float den = __shfl(accO[i], (lane & 32) | 8, 64);
            float val = accO[i] * frcp(den);
            int row = (i & 3) + 8 * (i >> 2) + 4 * hi;
            if (n < DK_) obase[(size_t)row * E_] = val;
        }
    }
}

// ---------------------------------------------------------------------------
// In-place output projection via f16 MFMA:  io[r][:] = io[r][:] @ Wc^T + bc.
// 128 blocks x 64 rows. A (64x128) and Wc (128x128) staged as f16 in 48KB LDS
// with 16B-chunk XOR swizzle; wave w owns row-group w&1, col-groups
// {2*(w>>1), 2*(w>>1)+1}; 8 K-steps of 32x32x16 mfma.
// ---------------------------------------------------------------------------
__global__ __launch_bounds__(256, 2)
void proj_mfma(const float* __restrict__ Wc, const float* __restrict__ bc,
               float* __restrict__ io) {
    __shared__ __align__(16) _Float16 As[64 * E_];   // 16KB
    __shared__ __align__(16) _Float16 Bs[E_ * E_];   // 32KB
    const int tid  = threadIdx.x;
    const int lane = tid & 63;
    const int wv   = tid >> 6;
    const int l31  = lane & 31;
    const int hi   = lane >> 5;
    const int r0   = blockIdx.x * 64;

    // stage A rows (io, fp32 -> f16) with chunk swizzle
    for (int i = tid; i < 64 * 16; i += 256) {
        int r = i >> 4, c = i & 15;
        const float* s = io + (size_t)(r0 + r) * E_ + c * 8;
        float4 a = *(const float4*)s;
        float4 b = *(const float4*)(s + 4);
        H2U p0, p1, p2, p3;
        p0.h = __builtin_amdgcn_cvt_pkrtz(a.x, a.y);
        p1.h = __builtin_amdgcn_cvt_pkrtz(a.z, a.w);
        p2.h = __builtin_amdgcn_cvt_pkrtz(b.x, b.y);
        p3.h = __builtin_amdgcn_cvt_pkrtz(b.z, b.w);
        *(uint4*)&As[r * E_ + ((c ^ (r & 7)) * 8)] = make_uint4(p0.u, p1.u, p2.u, p3.u);
    }
    // stage Wc (fp32 -> f16) with chunk swizzle
    for (int i = tid; i < E_ * 16; i += 256) {
        int r = i >> 4, c = i & 15;
        const float* s = Wc + (size_t)r * E_ + c * 8;
        float4 a = *(const float4*)s;
        float4 b = *(const float4*)(s + 4);
        H2U p0, p1, p2, p3;
        p0.h = __builtin_amdgcn_cvt_pkrtz(a.x, a.y);
        p1.h = __builtin_amdgcn_cvt_pkrtz(a.z, a.w);
        p2.h = __builtin_amdgcn_cvt_pkrtz(b.x, b.y);
        p3.h = __builtin_amdgcn_cvt_pkrtz(b.z, b.w);
        *(uint4*)&Bs[r * E_ + ((c ^ (r & 7)) * 8)] = make_uint4(p0.u, p1.u, p2.u, p3.u);
    }
    __syncthreads();

    const int rg = wv & 1;                // row-group: rows rg*32 + m
    const int cp = (wv >> 1) * 2;         // col-groups cp, cp+1

    f32x16 acc0 = {}, acc1 = {};
#pragma unroll
    for (int ks = 0; ks < 8; ++ks) {
        int ch = (ks * 2 + hi);
        f16x8 af  = *(const f16x8*)&As[(rg * 32 + l31) * E_ + ((ch ^ (l31 & 7)) * 8)];
        f16x8 bf0 = *(const f16x8*)&Bs[((cp + 0) * 32 + l31) * E_ + ((ch ^ (l31 & 7)) * 8)];
        f16x8 bf1 = *(const f16x8*)&Bs[((cp + 1) * 32 + l31) * E_ + ((ch ^ (l31 & 7)) * 8)];
        acc0 = __builtin_amdgcn_mfma_f32_32x32x16_f16(af, bf0, acc0, 0, 0, 0);
        acc1 = __builtin_amdgcn_mfma_f32_32x32x16_f16(af, bf1, acc1, 0, 0, 0);
    }

    const float b0 = bc[(cp + 0) * 32 + l31];
    const float b1 = bc[(cp + 1) * 32 + l31];
#pragma unroll
    for (int i = 0; i < 16; ++i) {
        int row = (i & 3) + 8 * (i >> 2) + 4 * hi;
        float* orow = io + (size_t)(r0 + rg * 32 + row) * E_;
        orow[(cp + 0) * 32 + l31] = acc0[i] + b0;
        orow[(cp + 1) * 32 + l31] = acc1[i] + b1;
    }
}

extern "C" void kernel_launch(void* const* d_in, const int* in_sizes, int n_in,
                              void* d_out, int out_size, void* d_ws, size_t ws_size,
                              hipStream_t stream) {
    const float* x     = (const float*)d_in[0];   // (4, 2048, 128)
    const float* theta = (const float*)d_in[1];   // (8,)
    const float* Wc    = (const float*)d_in[2];   // (128, 128)
    const float* bc    = (const float*)d_in[3];   // (128,)
    float* out = (float*)d_out;                   // (4, 2048, 128)

    qattn_mfma<<<dim3(S_ / 256, B_ * H_), 1024, 0, stream>>>(x, theta, out);
    proj_mfma<<<dim3((B_ * S_) / 64), 256, 0, stream>>>(Wc, bc, out);
}

// Round 10
// 50.569 us; speedup vs baseline: 1.2753x; 1.2753x over previous
//
#include <hip/hip_runtime.h>
#include <math.h>

#define B_  4
#define S_  2048
#define H_  16
#define DK_ 8
#define E_  128

typedef _Float16 f16x8  __attribute__((ext_vector_type(8)));
typedef __fp16   h2     __attribute__((ext_vector_type(2)));
typedef float    f32x16 __attribute__((ext_vector_type(16)));
typedef int      i32x2  __attribute__((ext_vector_type(2)));

union U4  { unsigned u[4]; f16x8 v; uint4 q; };
union H2U { h2 h; unsigned u; };

// log2(e)/sqrt(8): folds the 1/sqrt(dk) softmax scale and the exp->exp2 conversion
#define KSC 0.51006972f

static __device__ __forceinline__ float fexp2(float x) {
#if __has_builtin(__builtin_amdgcn_exp2f)
    return __builtin_amdgcn_exp2f(x);          // bare v_exp_f32
#else
    return __builtin_exp2f(x);
#endif
}

static __device__ __forceinline__ float frcp(float x) {
#if __has_builtin(__builtin_amdgcn_rcpf)
    return __builtin_amdgcn_rcpf(x);
#else
    return 1.0f / x;
#endif
}

// ---------------------------------------------------------------------------
// Fused quantum projection + attention, MFMA path, key-split waves.
// Block = 1024 thr (16 waves) = 8 q-groups x 2 key-halves; one (b,h) slice
// per blockIdx.y, 256 q-rows per block; LDS-merge of the two key-half
// partials (additive, no max bookkeeping). Round-10 change vs r7: the PV
// accumulator is SPLIT by PV-step (accP: keys 0-15, accQ: keys 16-31 of each
// tile). With a single accO, the two PV mfmas per tile + the next tile's PV
// serialize on the accumulator C-dependency (~140 cyc/tile unhideable chain
// = the ~130 cyc/tile bubble r5/r7/r8 couldn't move). Split chains are one
// MFMA per tile per acc with a full tile of work between -> hideable.
// ---------------------------------------------------------------------------
__global__ __launch_bounds__(1024, 8)
void qattn_mfma(const float* __restrict__ x, const float* __restrict__ theta,
                float* __restrict__ out) {
    constexpr int VST = 2056;                       // V^T row stride (bank-spread, 16B aligned)
    __shared__ __align__(16) _Float16 smem[S_ * DK_ + 9 * VST];
    _Float16* Klds = smem;                          // [2048][8]
    _Float16* Vt   = smem + S_ * DK_;               // [9][VST]

    const int tid  = threadIdx.x;
    const int lane = tid & 63;
    const int wv   = tid >> 6;                      // 0..15
    const int bh   = blockIdx.y;
    const int b    = bh >> 4;
    const int h    = bh & 15;

    // ---- stage cos(x+theta): K row-major + V^T (one key-pair per thread) ----
    {
        float th[DK_];
#pragma unroll
        for (int d = 0; d < DK_; ++d) th[d] = theta[d];

        const float* xp = x + ((size_t)b * S_) * E_ + h * DK_;
        const int s0 = tid * 2;
        float4 a0 = *(const float4*)(xp + (size_t)s0 * E_);
        float4 a1 = *(const float4*)(xp + (size_t)s0 * E_ + 4);
        float4 b0 = *(const float4*)(xp + (size_t)(s0 + 1) * E_);
        float4 b1 = *(const float4*)(xp + (size_t)(s0 + 1) * E_ + 4);
        float ca[8], cb[8];
        ca[0]=__cosf(a0.x+th[0]); ca[1]=__cosf(a0.y+th[1]); ca[2]=__cosf(a0.z+th[2]); ca[3]=__cosf(a0.w+th[3]);
        ca[4]=__cosf(a1.x+th[4]); ca[5]=__cosf(a1.y+th[5]); ca[6]=__cosf(a1.z+th[6]); ca[7]=__cosf(a1.w+th[7]);
        cb[0]=__cosf(b0.x+th[0]); cb[1]=__cosf(b0.y+th[1]); cb[2]=__cosf(b0.z+th[2]); cb[3]=__cosf(b0.w+th[3]);
        cb[4]=__cosf(b1.x+th[4]); cb[5]=__cosf(b1.y+th[5]); cb[6]=__cosf(b1.z+th[6]); cb[7]=__cosf(b1.w+th[7]);

        H2U p0, p1, p2, p3;
        p0.h = __builtin_amdgcn_cvt_pkrtz(ca[0], ca[1]);
        p1.h = __builtin_amdgcn_cvt_pkrtz(ca[2], ca[3]);
        p2.h = __builtin_amdgcn_cvt_pkrtz(ca[4], ca[5]);
        p3.h = __builtin_amdgcn_cvt_pkrtz(ca[6], ca[7]);
        *(uint4*)&Klds[(size_t)s0 * DK_] = make_uint4(p0.u, p1.u, p2.u, p3.u);
        p0.h = __builtin_amdgcn_cvt_pkrtz(cb[0], cb[1]);
        p1.h = __builtin_amdgcn_cvt_pkrtz(cb[2], cb[3]);
        p2.h = __builtin_amdgcn_cvt_pkrtz(cb[4], cb[5]);
        p3.h = __builtin_amdgcn_cvt_pkrtz(cb[6], cb[7]);
        *(uint4*)&Klds[(size_t)(s0 + 1) * DK_] = make_uint4(p0.u, p1.u, p2.u, p3.u);

#pragma unroll
        for (int d = 0; d < DK_; ++d) {             // V^T: (key s0, s0+1) pair
            H2U tv; tv.h = __builtin_amdgcn_cvt_pkrtz(ca[d], cb[d]);
            *(unsigned*)&Vt[d * VST + s0] = tv.u;
        }
        *(unsigned*)&Vt[8 * VST + s0] = 0x3C003C00u;  // ones row -> denominator
    }
    __syncthreads();

    // ---- wave = (q-group, key-half) ----
    const int  qg    = wv & 7;
    const int  kh    = wv >> 3;
    const int  qrow0 = blockIdx.x * 256 + qg * 32;
    const int  t0    = kh * 32;                     // this wave's first key-tile
    const int  l31   = lane & 31;
    const int  hi    = lane >> 5;
    const bool lo32  = (lane < 32);

    f16x8 qf = {};                                  // Q^T B-frag: lanes>=32 zero (dims 8..15)
    if (lo32) {
        qf = *(const f16x8*)&Klds[(size_t)(qrow0 + l31) * DK_];
#pragma unroll
        for (int d = 0; d < DK_; ++d)               // fold softmax scale + log2e into Q
            qf[d] = qf[d] * (_Float16)KSC;
    }

    const f32x16 z16 = {};                          // constant zero C operand
    f32x16 accP = {}, accQ = {};                    // split O accumulators (by PV step)

    const int nc = (l31 <= 8) ? l31 : 8;            // clamp unused cols to ones row
    const _Float16* vbase = &Vt[nc * VST + hi * 8];

    // kf loads are unconditional: lanes>=32 duplicate their l31 partner's row;
    // their A-contribution hits qf's zeroed k=8..15 half -> 0.
#pragma unroll 2
    for (int kt = t0; kt < t0 + 32; ++kt) {
        f16x8 kf = *(const f16x8*)&Klds[(size_t)(kt * 32 + l31) * DK_];
        // S^T[key][qrow] for 32 keys x 32 qrows; lane holds 16 keys of qrow=lane&31
        f32x16 sc = __builtin_amdgcn_mfma_f32_32x32x16_f16(kf, qf, z16, 0, 0, 0);

        unsigned X[4][2];                           // X[q] = f16 pair-packed exp(scores)
#pragma unroll
        for (int q = 0; q < 4; ++q) {
            float w0 = fexp2(sc[4 * q + 0]);
            float w1 = fexp2(sc[4 * q + 1]);
            float w2 = fexp2(sc[4 * q + 2]);
            float w3 = fexp2(sc[4 * q + 3]);
            H2U p0, p1;
            p0.h = __builtin_amdgcn_cvt_pkrtz(w0, w1);
            p1.h = __builtin_amdgcn_cvt_pkrtz(w2, w3);
            X[q][0] = p0.u; X[q][1] = p1.u;
        }

        // PV step s=0 -> accP, s=1 -> accQ: two independent MFMA chains
        {
            U4 pa;
#pragma unroll
            for (int i = 0; i < 2; ++i) {
                i32x2 r = __builtin_amdgcn_permlane32_swap(
                    (int)X[0][i], (int)X[1][i], false, false);
                pa.u[i]     = (unsigned)r[0];       // keys j=0..3 (from hi=0 half)
                pa.u[2 + i] = (unsigned)r[1];       // keys j=4..7 (from hi=1 half)
            }
            f16x8 vf = *(const f16x8*)(vbase + kt * 32);
            accP = __builtin_amdgcn_mfma_f32_32x32x16_f16(pa.v, vf, accP, 0, 0, 0);
        }
        {
            U4 pa;
#pragma unroll
            for (int i = 0; i < 2; ++i) {
                i32x2 r = __builtin_amdgcn_permlane32_swap(
                    (int)X[2][i], (int)X[3][i], false, false);
                pa.u[i]     = (unsigned)r[0];
                pa.u[2 + i] = (unsigned)r[1];
            }
            f16x8 vf = *(const f16x8*)(vbase + kt * 32 + 16);
            accQ = __builtin_amdgcn_mfma_f32_32x32x16_f16(pa.v, vf, accQ, 0, 0, 0);
        }
    }

    f32x16 accO;
#pragma unroll
    for (int i = 0; i < 16; ++i) accO[i] = accP[i] + accQ[i];

    // ---- merge key-halves: kh=1 waves dump accO to LDS, kh=0 waves add ----
    __syncthreads();                                // all LDS reads done
    float* scratch = (float*)smem;                  // reuse Klds region, 32KB
    if (kh == 1) {
        float4* dst = (float4*)&scratch[(size_t)(qg * 64 + lane) * 16];
#pragma unroll
        for (int i = 0; i < 4; ++i)
            dst[i] = make_float4(accO[4*i], accO[4*i+1], accO[4*i+2], accO[4*i+3]);
    }
    __syncthreads();
    if (kh == 0) {
        const float4* src = (const float4*)&scratch[(size_t)(qg * 64 + lane) * 16];
#pragma unroll
        for (int i = 0; i < 4; ++i) {
            float4 p = src[i];
            accO[4*i+0] += p.x; accO[4*i+1] += p.y;
            accO[4*i+2] += p.z; accO[4*i+3] += p.w;
        }

        // ---- epilogue: normalize by col-8 (ones column) and store ----
        const int n = l31;
        float* obase = out + ((size_t)(b * S_ + qrow0)) * E_ + h * DK_ + n;
#pragma unroll
        for (int i = 0; i < 16; ++i) {
            float den = __shfl(accO[i], (lane & 32) | 8, 64);
            float val = accO[i] * frcp(den);
            int row = (i & 3) + 8 * (i >> 2) + 4 * hi;
            if (n < DK_) obase[(size_t)row * E_] = val;
        }
    }
}

// ---------------------------------------------------------------------------
// In-place output projection via f16 MFMA:  io[r][:] = io[r][:] @ Wc^T + bc.
// 128 blocks x 64 rows. A (64x128) and Wc (128x128) staged as f16 in 48KB LDS
// with 16B-chunk XOR swizzle; wave w owns row-group w&1, col-groups
// {2*(w>>1), 2*(w>>1)+1}; 8 K-steps of 32x32x16 mfma.
// ---------------------------------------------------------------------------
__global__ __launch_bounds__(256, 2)
void proj_mfma(const float* __restrict__ Wc, const float* __restrict__ bc,
               float* __restrict__ io) {
    __shared__ __align__(16) _Float16 As[64 * E_];   // 16KB
    __shared__ __align__(16) _Float16 Bs[E_ * E_];   // 32KB
    const int tid  = threadIdx.x;
    const int lane = tid & 63;
    const int wv   = tid >> 6;
    const int l31  = lane & 31;
    const int hi   = lane >> 5;
    const int r0   = blockIdx.x * 64;

    // stage A rows (io, fp32 -> f16) with chunk swizzle
    for (int i = tid; i < 64 * 16; i += 256) {
        int r = i >> 4, c = i & 15;
        const float* s = io + (size_t)(r0 + r) * E_ + c * 8;
        float4 a = *(const float4*)s;
        float4 b = *(const float4*)(s + 4);
        H2U p0, p1, p2, p3;
        p0.h = __builtin_amdgcn_cvt_pkrtz(a.x, a.y);
        p1.h = __builtin_amdgcn_cvt_pkrtz(a.z, a.w);
        p2.h = __builtin_amdgcn_cvt_pkrtz(b.x, b.y);
        p3.h = __builtin_amdgcn_cvt_pkrtz(b.z, b.w);
        *(uint4*)&As[r * E_ + ((c ^ (r & 7)) * 8)] = make_uint4(p0.u, p1.u, p2.u, p3.u);
    }
    // stage Wc (fp32 -> f16) with chunk swizzle
    for (int i = tid; i < E_ * 16; i += 256) {
        int r = i >> 4, c = i & 15;
        const float* s = Wc + (size_t)r * E_ + c * 8;
        float4 a = *(const float4*)s;
        float4 b = *(const float4*)(s + 4);
        H2U p0, p1, p2, p3;
        p0.h = __builtin_amdgcn_cvt_pkrtz(a.x, a.y);
        p1.h = __builtin_amdgcn_cvt_pkrtz(a.z, a.w);
        p2.h = __builtin_amdgcn_cvt_pkrtz(b.x, b.y);
        p3.h = __builtin_amdgcn_cvt_pkrtz(b.z, b.w);
        *(uint4*)&Bs[r * E_ + ((c ^ (r & 7)) * 8)] = make_uint4(p0.u, p1.u, p2.u, p3.u);
    }
    __syncthreads();

    const int rg = wv & 1;                // row-group: rows rg*32 + m
    const int cp = (wv >> 1) * 2;         // col-groups cp, cp+1

    f32x16 acc0 = {}, acc1 = {};
#pragma unroll
    for (int ks = 0; ks < 8; ++ks) {
        int ch = (ks * 2 + hi);
        f16x8 af  = *(const f16x8*)&As[(rg * 32 + l31) * E_ + ((ch ^ (l31 & 7)) * 8)];
        f16x8 bf0 = *(const f16x8*)&Bs[((cp + 0) * 32 + l31) * E_ + ((ch ^ (l31 & 7)) * 8)];
        f16x8 bf1 = *(const f16x8*)&Bs[((cp + 1) * 32 + l31) * E_ + ((ch ^ (l31 & 7)) * 8)];
        acc0 = __builtin_amdgcn_mfma_f32_32x32x16_f16(af, bf0, acc0, 0, 0, 0);
        acc1 = __builtin_amdgcn_mfma_f32_32x32x16_f16(af, bf1, acc1, 0, 0, 0);
    }

    const float b0 = bc[(cp + 0) * 32 + l31];
    const float b1 = bc[(cp + 1) * 32 + l31];
#pragma unroll
    for (int i = 0; i < 16; ++i) {
        int row = (i & 3) + 8 * (i >> 2) + 4 * hi;
        float* orow = io + (size_t)(r0 + rg * 32 + row) * E_;
        orow[(cp + 0) * 32 + l31] = acc0[i] + b0;
        orow[(cp + 1) * 32 + l31] = acc1[i] + b1;
    }
}

extern "C" void kernel_launch(void* const* d_in, const int* in_sizes, int n_in,
                              void* d_out, int out_size, void* d_ws, size_t ws_size,
                              hipStream_t stream) {
    const float* x     = (const float*)d_in[0];   // (4, 2048, 128)
    const float* theta = (const float*)d_in[1];   // (8,)
    const float* Wc    = (const float*)d_in[2];   // (128, 128)
    const float* bc    = (const float*)d_in[3];   // (128,)
    float* out = (float*)d_out;                   // (4, 2048, 128)

    qattn_mfma<<<dim3(S_ / 256, B_ * H_), 1024, 0, stream>>>(x, theta, out);
    proj_mfma<<<dim3((B_ * S_) / 64), 256, 0, stream>>>(Wc, bc, out);
}

// Round 11
// 46.185 us; speedup vs baseline: 1.3963x; 1.0949x over previous
//
#include <hip/hip_runtime.h>
#include <math.h>

#define B_  4
#define S_  2048
#define H_  16
#define DK_ 8
#define E_  128

typedef _Float16 f16x8  __attribute__((ext_vector_type(8)));
typedef __fp16   h2     __attribute__((ext_vector_type(2)));
typedef float    f32x16 __attribute__((ext_vector_type(16)));
typedef int      i32x2  __attribute__((ext_vector_type(2)));

union U4  { unsigned u[4]; f16x8 v; uint4 q; };
union H2U { h2 h; unsigned u; };

// log2(e)/sqrt(8): folds the 1/sqrt(dk) softmax scale and the exp->exp2 conversion
#define KSC 0.51006972f

static __device__ __forceinline__ float fexp2(float x) {
#if __has_builtin(__builtin_amdgcn_exp2f)
    return __builtin_amdgcn_exp2f(x);          // bare v_exp_f32
#else
    return __builtin_exp2f(x);
#endif
}

static __device__ __forceinline__ float frcp(float x) {
#if __has_builtin(__builtin_amdgcn_rcpf)
    return __builtin_amdgcn_rcpf(x);
#else
    return 1.0f / x;
#endif
}

// ---------------------------------------------------------------------------
// Fused quantum projection + attention, MFMA path, 2-stage software pipeline.
// Block = 512 thr (8 waves), one (b,h) slice per blockIdx.y, 256 q-rows per
// block (32 per wave), 64 key-tiles per wave. Two rotating score registers
// (scA/scB): while tile t's exp/pack runs on the VALU, tile t+1's QK^T mfma
// (issued last step) completes, and tile t+2's QK^T is issued right after
// the exp reads free the register. PV accumulators split (accP/accQ) so the
// two PV mfmas per tile form independent C-chains. This attacks the measured
// per-wave serial chain (~1600 cyc/tile vs 212 cyc issue work) that
// occupancy (r7), phase-locked ILP (r8), and load prefetch (r5) all missed.
// 4 waves/SIMD (128-VGPR budget, est ~105 used -> no spill, unlike r10).
// ---------------------------------------------------------------------------
__global__ __launch_bounds__(512, 4)
void qattn_mfma(const float* __restrict__ x, const float* __restrict__ theta,
                float* __restrict__ out) {
    constexpr int VST = 2056;                       // V^T row stride (bank-spread, 16B aligned)
    __shared__ __align__(16) _Float16 smem[S_ * DK_ + 9 * VST];
    _Float16* Klds = smem;                          // [2048][8]
    _Float16* Vt   = smem + S_ * DK_;               // [9][VST]

    const int tid  = threadIdx.x;
    const int lane = tid & 63;
    const int wv   = tid >> 6;
    const int bh   = blockIdx.y;
    const int b    = bh >> 4;
    const int h    = bh & 15;

    // ---- stage cos(x+theta): K row-major + V^T (pairs of keys) ----
    {
        float th[DK_];
#pragma unroll
        for (int d = 0; d < DK_; ++d) th[d] = theta[d];

        const float* xp = x + ((size_t)b * S_) * E_ + h * DK_;
#pragma unroll
        for (int m = 0; m < 2; ++m) {
            const int s0 = tid * 4 + 2 * m;
            float4 a0 = *(const float4*)(xp + (size_t)s0 * E_);
            float4 a1 = *(const float4*)(xp + (size_t)s0 * E_ + 4);
            float4 b0 = *(const float4*)(xp + (size_t)(s0 + 1) * E_);
            float4 b1 = *(const float4*)(xp + (size_t)(s0 + 1) * E_ + 4);
            float ca[8], cb[8];
            ca[0]=__cosf(a0.x+th[0]); ca[1]=__cosf(a0.y+th[1]); ca[2]=__cosf(a0.z+th[2]); ca[3]=__cosf(a0.w+th[3]);
            ca[4]=__cosf(a1.x+th[4]); ca[5]=__cosf(a1.y+th[5]); ca[6]=__cosf(a1.z+th[6]); ca[7]=__cosf(a1.w+th[7]);
            cb[0]=__cosf(b0.x+th[0]); cb[1]=__cosf(b0.y+th[1]); cb[2]=__cosf(b0.z+th[2]); cb[3]=__cosf(b0.w+th[3]);
            cb[4]=__cosf(b1.x+th[4]); cb[5]=__cosf(b1.y+th[5]); cb[6]=__cosf(b1.z+th[6]); cb[7]=__cosf(b1.w+th[7]);

            H2U p0, p1, p2, p3;
            p0.h = __builtin_amdgcn_cvt_pkrtz(ca[0], ca[1]);
            p1.h = __builtin_amdgcn_cvt_pkrtz(ca[2], ca[3]);
            p2.h = __builtin_amdgcn_cvt_pkrtz(ca[4], ca[5]);
            p3.h = __builtin_amdgcn_cvt_pkrtz(ca[6], ca[7]);
            *(uint4*)&Klds[(size_t)s0 * DK_] = make_uint4(p0.u, p1.u, p2.u, p3.u);
            p0.h = __builtin_amdgcn_cvt_pkrtz(cb[0], cb[1]);
            p1.h = __builtin_amdgcn_cvt_pkrtz(cb[2], cb[3]);
            p2.h = __builtin_amdgcn_cvt_pkrtz(cb[4], cb[5]);
            p3.h = __builtin_amdgcn_cvt_pkrtz(cb[6], cb[7]);
            *(uint4*)&Klds[(size_t)(s0 + 1) * DK_] = make_uint4(p0.u, p1.u, p2.u, p3.u);

#pragma unroll
            for (int d = 0; d < DK_; ++d) {         // V^T: (key s0, s0+1) pair
                H2U tv; tv.h = __builtin_amdgcn_cvt_pkrtz(ca[d], cb[d]);
                *(unsigned*)&Vt[d * VST + s0] = tv.u;
            }
            *(unsigned*)&Vt[8 * VST + s0] = 0x3C003C00u;  // ones row -> denominator
        }
    }
    __syncthreads();

    // ---- per-wave 32 q-rows over all 2048 keys ----
    const int  qrow0 = blockIdx.x * 256 + wv * 32;
    const int  l31   = lane & 31;
    const int  hi    = lane >> 5;
    const bool lo32  = (lane < 32);

    f16x8 qf = {};                                  // Q^T B-frag: lanes>=32 zero (dims 8..15)
    if (lo32) {
        qf = *(const f16x8*)&Klds[(size_t)(qrow0 + l31) * DK_];
#pragma unroll
        for (int d = 0; d < DK_; ++d)               // fold softmax scale + log2e into Q
            qf[d] = qf[d] * (_Float16)KSC;
    }

    const f32x16 z16 = {};                          // constant zero C operand
    f32x16 accP = {}, accQ = {};                    // split O accumulators (by PV step)

    const int nc = (l31 <= 8) ? l31 : 8;            // clamp unused cols to ones row
    const _Float16* vbase = &Vt[nc * VST + hi * 8];

    // kf loads are unconditional: lanes>=32 duplicate their l31 partner's row;
    // their A-contribution hits qf's zeroed k=8..15 half -> 0.
#define LDK(T)    (*(const f16x8*)&Klds[(size_t)(((T) * 32) + l31) * DK_])
#define LDV(T, S) (*(const f16x8*)(vbase + ((T) * 32) + (S) * 16))

    // exp/pack + PV of tile T reading SC; then (optionally) refill SC with
    // tile TN's QK^T -- issued between the last SC read and the PV mfmas so
    // its latency hides under the next PROC's exp phase.
#define PROC(SC, T, TN, REFILL)                                                \
    {                                                                          \
        unsigned X[4][2];                                                      \
        _Pragma("unroll")                                                      \
        for (int q = 0; q < 4; ++q) {                                          \
            float w0 = fexp2(SC[4*q+0]);                                       \
            float w1 = fexp2(SC[4*q+1]);                                       \
            float w2 = fexp2(SC[4*q+2]);                                       \
            float w3 = fexp2(SC[4*q+3]);                                       \
            H2U p0, p1;                                                        \
            p0.h = __builtin_amdgcn_cvt_pkrtz(w0, w1);                         \
            p1.h = __builtin_amdgcn_cvt_pkrtz(w2, w3);                         \
            X[q][0] = p0.u; X[q][1] = p1.u;                                    \
        }                                                                      \
        if (REFILL)                                                            \
            SC = __builtin_amdgcn_mfma_f32_32x32x16_f16(LDK(TN), qf, z16,      \
                                                        0, 0, 0);              \
        {                                                                      \
            U4 pa;                                                             \
            _Pragma("unroll")                                                  \
            for (int i = 0; i < 2; ++i) {                                      \
                i32x2 r = __builtin_amdgcn_permlane32_swap(                    \
                    (int)X[0][i], (int)X[1][i], false, false);                 \
                pa.u[i]     = (unsigned)r[0];                                  \
                pa.u[2 + i] = (unsigned)r[1];                                  \
            }                                                                  \
            accP = __builtin_amdgcn_mfma_f32_32x32x16_f16(                     \
                pa.v, LDV(T, 0), accP, 0, 0, 0);                               \
        }                                                                      \
        {                                                                      \
            U4 pa;                                                             \
            _Pragma("unroll")                                                  \
            for (int i = 0; i < 2; ++i) {                                      \
                i32x2 r = __builtin_amdgcn_permlane32_swap(                    \
                    (int)X[2][i], (int)X[3][i], false, false);                 \
                pa.u[i]     = (unsigned)r[0];                                  \
                pa.u[2 + i] = (unsigned)r[1];                                  \
            }                                                                  \
            accQ = __builtin_amdgcn_mfma_f32_32x32x16_f16(                     \
                pa.v, LDV(T, 1), accQ, 0, 0, 0);                               \
        }                                                                      \
    }

    f32x16 scA = __builtin_amdgcn_mfma_f32_32x32x16_f16(LDK(0), qf, z16, 0, 0, 0);
    f32x16 scB = __builtin_amdgcn_mfma_f32_32x32x16_f16(LDK(1), qf, z16, 0, 0, 0);

    for (int kt = 0; kt < 62; kt += 2) {
        PROC(scA, kt,     kt + 2, 1)
        PROC(scB, kt + 1, kt + 3, 1)
    }
    PROC(scA, 62, 0, 0)                             // tails: no refill
    PROC(scB, 63, 0, 0)
#undef PROC
#undef LDK
#undef LDV

    f32x16 accO;
#pragma unroll
    for (int i = 0; i < 16; ++i) accO[i] = accP[i] + accQ[i];

    // ---- epilogue: normalize by col-8 (ones column) and store ----
    const int n = l31;
    float* obase = out + ((size_t)(b * S_ + qrow0)) * E_ + h * DK_ + n;
#pragma unroll
    for (int i = 0; i < 16; ++i) {
        float den = __shfl(accO[i], (lane & 32) | 8, 64);
        float val = accO[i] * frcp(den);
        int row = (i & 3) + 8 * (i >> 2) + 4 * hi;
        if (n < DK_) obase[(size_t)row * E_] = val;
    }
}

// ---------------------------------------------------------------------------
// In-place output projection via f16 MFMA:  io[r][:] = io[r][:] @ Wc^T + bc.
// 128 blocks x 64 rows. A (64x128) and Wc (128x128) staged as f16 in 48KB LDS
// with 16B-chunk XOR swizzle; wave w owns row-group w&1, col-groups
// {2*(w>>1), 2*(w>>1)+1}; 8 K-steps of 32x32x16 mfma.
// ---------------------------------------------------------------------------
__global__ __launch_bounds__(256, 2)
void proj_mfma(const float* __restrict__ Wc, const float* __restrict__ bc,
               float* __restrict__ io) {
    __shared__ __align__(16) _Float16 As[64 * E_];   // 16KB
    __shared__ __align__(16) _Float16 Bs[E_ * E_];   // 32KB
    const int tid  = threadIdx.x;
    const int lane = tid & 63;
    const int wv   = tid >> 6;
    const int l31  = lane & 31;
    const int hi   = lane >> 5;
    const int r0   = blockIdx.x * 64;

    // stage A rows (io, fp32 -> f16) with chunk swizzle
    for (int i = tid; i < 64 * 16; i += 256) {
        int r = i >> 4, c = i & 15;
        const float* s = io + (size_t)(r0 + r) * E_ + c * 8;
        float4 a = *(const float4*)s;
        float4 b = *(const float4*)(s + 4);
        H2U p0, p1, p2, p3;
        p0.h = __builtin_amdgcn_cvt_pkrtz(a.x, a.y);
        p1.h = __builtin_amdgcn_cvt_pkrtz(a.z, a.w);
        p2.h = __builtin_amdgcn_cvt_pkrtz(b.x, b.y);
        p3.h = __builtin_amdgcn_cvt_pkrtz(b.z, b.w);
        *(uint4*)&As[r * E_ + ((c ^ (r & 7)) * 8)] = make_uint4(p0.u, p1.u, p2.u, p3.u);
    }
    // stage Wc (fp32 -> f16) with chunk swizzle
    for (int i = tid; i < E_ * 16; i += 256) {
        int r = i >> 4, c = i & 15;
        const float* s = Wc + (size_t)r * E_ + c * 8;
        float4 a = *(const float4*)s;
        float4 b = *(const float4*)(s + 4);
        H2U p0, p1, p2, p3;
        p0.h = __builtin_amdgcn_cvt_pkrtz(a.x, a.y);
        p1.h = __builtin_amdgcn_cvt_pkrtz(a.z, a.w);
        p2.h = __builtin_amdgcn_cvt_pkrtz(b.x, b.y);
        p3.h = __builtin_amdgcn_cvt_pkrtz(b.z, b.w);
        *(uint4*)&Bs[r * E_ + ((c ^ (r & 7)) * 8)] = make_uint4(p0.u, p1.u, p2.u, p3.u);
    }
    __syncthreads();

    const int rg = wv & 1;                // row-group: rows rg*32 + m
    const int cp = (wv >> 1) * 2;         // col-groups cp, cp+1

    f32x16 acc0 = {}, acc1 = {};
#pragma unroll
    for (int ks = 0; ks < 8; ++ks) {
        int ch = (ks * 2 + hi);
        f16x8 af  = *(const f16x8*)&As[(rg * 32 + l31) * E_ + ((ch ^ (l31 & 7)) * 8)];
        f16x8 bf0 = *(const f16x8*)&Bs[((cp + 0) * 32 + l31) * E_ + ((ch ^ (l31 & 7)) * 8)];
        f16x8 bf1 = *(const f16x8*)&Bs[((cp + 1) * 32 + l31) * E_ + ((ch ^ (l31 & 7)) * 8)];
        acc0 = __builtin_amdgcn_mfma_f32_32x32x16_f16(af, bf0, acc0, 0, 0, 0);
        acc1 = __builtin_amdgcn_mfma_f32_32x32x16_f16(af, bf1, acc1, 0, 0, 0);
    }

    const float b0 = bc[(cp + 0) * 32 + l31];
    const float b1 = bc[(cp + 1) * 32 + l31];
#pragma unroll
    for (int i = 0; i < 16; ++i) {
        int row = (i & 3) + 8 * (i >> 2) + 4 * hi;
        float* orow = io + (size_t)(r0 + rg * 32 + row) * E_;
        orow[(cp + 0) * 32 + l31] = acc0[i] + b0;
        orow[(cp + 1) * 32 + l31] = acc1[i] + b1;
    }
}

extern "C" void kernel_launch(void* const* d_in, const int* in_sizes, int n_in,
                              void* d_out, int out_size, void* d_ws, size_t ws_size,
                              hipStream_t stream) {
    const float* x     = (const float*)d_in[0];   // (4, 2048, 128)
    const float* theta = (const float*)d_in[1];   // (8,)
    const float* Wc    = (const float*)d_in[2];   // (128, 128)
    const float* bc    = (const float*)d_in[3];   // (128,)
    float* out = (float*)d_out;                   // (4, 2048, 128)

    qattn_mfma<<<dim3(S_ / 256, B_ * H_), 512, 0, stream>>>(x, theta, out);
    proj_mfma<<<dim3((B_ * S_) / 64), 256, 0, stream>>>(Wc, bc, out);
}

// Round 12
// 45.847 us; speedup vs baseline: 1.4066x; 1.0074x over previous
//
#include <hip/hip_runtime.h>
#include <math.h>

#define B_  4
#define S_  2048
#define H_  16
#define DK_ 8
#define E_  128

typedef _Float16 f16x8  __attribute__((ext_vector_type(8)));
typedef __fp16   h2     __attribute__((ext_vector_type(2)));
typedef float    f32x16 __attribute__((ext_vector_type(16)));
typedef int      i32x2  __attribute__((ext_vector_type(2)));

union U4  { unsigned u[4]; f16x8 v; uint4 q; };
union H2U { h2 h; unsigned u; };

// log2(e)/sqrt(8): folds the 1/sqrt(dk) softmax scale and the exp->exp2 conversion
#define KSC 0.51006972f

static __device__ __forceinline__ float fexp2(float x) {
#if __has_builtin(__builtin_amdgcn_exp2f)
    return __builtin_amdgcn_exp2f(x);          // bare v_exp_f32
#else
    return __builtin_exp2f(x);
#endif
}

static __device__ __forceinline__ float frcp(float x) {
#if __has_builtin(__builtin_amdgcn_rcpf)
    return __builtin_amdgcn_rcpf(x);
#else
    return 1.0f / x;
#endif
}

// ---------------------------------------------------------------------------
// Fused quantum projection + attention, MFMA path, 2-stage software pipeline.
// Block = 512 thr (8 waves), one (b,h) slice per blockIdx.y, 256 q-rows per
// block (32 per wave), 64 key-tiles per wave. r12 changes vs r11 (VALU diet;
// model: wall ~= VALU_work/0.53 across r4..r11):
//   - all LDS reads are base-VGPR + literal immediate offset (kbyte/vbyte
//     hoisted, #pragma unroll 4 makes in-body offsets compile-time)
//   - s_setprio(1) around the MFMA cluster (SALU: free on VALU pipe)
// ---------------------------------------------------------------------------
__global__ __launch_bounds__(512, 4)
void qattn_mfma(const float* __restrict__ x, const float* __restrict__ theta,
                float* __restrict__ out) {
    constexpr int VST = 2056;                       // V^T row stride (bank-spread, 16B aligned)
    __shared__ __align__(16) _Float16 smem[S_ * DK_ + 9 * VST];
    _Float16* Klds = smem;                          // [2048][8]
    _Float16* Vt   = smem + S_ * DK_;               // [9][VST]

    const int tid  = threadIdx.x;
    const int lane = tid & 63;
    const int wv   = tid >> 6;
    const int bh   = blockIdx.y;
    const int b    = bh >> 4;
    const int h    = bh & 15;

    // ---- stage cos(x+theta): K row-major + V^T (pairs of keys) ----
    {
        float th[DK_];
#pragma unroll
        for (int d = 0; d < DK_; ++d) th[d] = theta[d];

        const float* xp = x + ((size_t)b * S_) * E_ + h * DK_;
#pragma unroll
        for (int m = 0; m < 2; ++m) {
            const int s0 = tid * 4 + 2 * m;
            float4 a0 = *(const float4*)(xp + (size_t)s0 * E_);
            float4 a1 = *(const float4*)(xp + (size_t)s0 * E_ + 4);
            float4 b0 = *(const float4*)(xp + (size_t)(s0 + 1) * E_);
            float4 b1 = *(const float4*)(xp + (size_t)(s0 + 1) * E_ + 4);
            float ca[8], cb[8];
            ca[0]=__cosf(a0.x+th[0]); ca[1]=__cosf(a0.y+th[1]); ca[2]=__cosf(a0.z+th[2]); ca[3]=__cosf(a0.w+th[3]);
            ca[4]=__cosf(a1.x+th[4]); ca[5]=__cosf(a1.y+th[5]); ca[6]=__cosf(a1.z+th[6]); ca[7]=__cosf(a1.w+th[7]);
            cb[0]=__cosf(b0.x+th[0]); cb[1]=__cosf(b0.y+th[1]); cb[2]=__cosf(b0.z+th[2]); cb[3]=__cosf(b0.w+th[3]);
            cb[4]=__cosf(b1.x+th[4]); cb[5]=__cosf(b1.y+th[5]); cb[6]=__cosf(b1.z+th[6]); cb[7]=__cosf(b1.w+th[7]);

            H2U p0, p1, p2, p3;
            p0.h = __builtin_amdgcn_cvt_pkrtz(ca[0], ca[1]);
            p1.h = __builtin_amdgcn_cvt_pkrtz(ca[2], ca[3]);
            p2.h = __builtin_amdgcn_cvt_pkrtz(ca[4], ca[5]);
            p3.h = __builtin_amdgcn_cvt_pkrtz(ca[6], ca[7]);
            *(uint4*)&Klds[(size_t)s0 * DK_] = make_uint4(p0.u, p1.u, p2.u, p3.u);
            p0.h = __builtin_amdgcn_cvt_pkrtz(cb[0], cb[1]);
            p1.h = __builtin_amdgcn_cvt_pkrtz(cb[2], cb[3]);
            p2.h = __builtin_amdgcn_cvt_pkrtz(cb[4], cb[5]);
            p3.h = __builtin_amdgcn_cvt_pkrtz(cb[6], cb[7]);
            *(uint4*)&Klds[(size_t)(s0 + 1) * DK_] = make_uint4(p0.u, p1.u, p2.u, p3.u);

#pragma unroll
            for (int d = 0; d < DK_; ++d) {         // V^T: (key s0, s0+1) pair
                H2U tv; tv.h = __builtin_amdgcn_cvt_pkrtz(ca[d], cb[d]);
                *(unsigned*)&Vt[d * VST + s0] = tv.u;
            }
            *(unsigned*)&Vt[8 * VST + s0] = 0x3C003C00u;  // ones row -> denominator
        }
    }
    __syncthreads();

    // ---- per-wave 32 q-rows over all 2048 keys ----
    const int  qrow0 = blockIdx.x * 256 + wv * 32;
    const int  l31   = lane & 31;
    const int  hi    = lane >> 5;
    const bool lo32  = (lane < 32);

    f16x8 qf = {};                                  // Q^T B-frag: lanes>=32 zero (dims 8..15)
    if (lo32) {
        qf = *(const f16x8*)&Klds[(size_t)(qrow0 + l31) * DK_];
#pragma unroll
        for (int d = 0; d < DK_; ++d)               // fold softmax scale + log2e into Q
            qf[d] = qf[d] * (_Float16)KSC;
    }

    const f32x16 z16 = {};                          // constant zero C operand
    f32x16 accP = {}, accQ = {};                    // split O accumulators (by PV step)

    const int nc = (l31 <= 8) ? l31 : 8;            // clamp unused cols to ones row

    // hoisted byte-base pointers: every LDS read below is base + literal
    // immediate (kt*512 <= 32KB, kt*64+32 <= 4KB -- both fit ds offset:)
    const char* kbyte = (const char*)&Klds[(size_t)l31 * DK_];
    const char* vbyte = (const char*)&Vt[(size_t)nc * VST + hi * 8];

    // kf loads are unconditional: lanes>=32 duplicate their l31 partner's row;
    // their A-contribution hits qf's zeroed k=8..15 half -> 0.
#define LDK(T)    (*(const f16x8*)(kbyte + (size_t)(T) * 512))
#define LDV(T, S) (*(const f16x8*)(vbyte + (size_t)(T) * 64 + (S) * 32))

    // exp/pack of tile T from SC; setprio(1) around the MFMA cluster
    // (QK refill for tile TN + both PV mfmas), setprio(0) after.
#define PROC(SC, T, TN, REFILL)                                                \
    {                                                                          \
        unsigned X[4][2];                                                      \
        _Pragma("unroll")                                                      \
        for (int q = 0; q < 4; ++q) {                                          \
            float w0 = fexp2(SC[4*q+0]);                                       \
            float w1 = fexp2(SC[4*q+1]);                                       \
            float w2 = fexp2(SC[4*q+2]);                                       \
            float w3 = fexp2(SC[4*q+3]);                                       \
            H2U p0, p1;                                                        \
            p0.h = __builtin_amdgcn_cvt_pkrtz(w0, w1);                         \
            p1.h = __builtin_amdgcn_cvt_pkrtz(w2, w3);                         \
            X[q][0] = p0.u; X[q][1] = p1.u;                                    \
        }                                                                      \
        __builtin_amdgcn_s_setprio(1);                                         \
        if (REFILL)                                                            \
            SC = __builtin_amdgcn_mfma_f32_32x32x16_f16(LDK(TN), qf, z16,      \
                                                        0, 0, 0);              \
        {                                                                      \
            U4 pa;                                                             \
            _Pragma("unroll")                                                  \
            for (int i = 0; i < 2; ++i) {                                      \
                i32x2 r = __builtin_amdgcn_permlane32_swap(                    \
                    (int)X[0][i], (int)X[1][i], false, false);                 \
                pa.u[i]     = (unsigned)r[0];                                  \
                pa.u[2 + i] = (unsigned)r[1];                                  \
            }                                                                  \
            accP = __builtin_amdgcn_mfma_f32_32x32x16_f16(                     \
                pa.v, LDV(T, 0), accP, 0, 0, 0);                               \
        }                                                                      \
        {                                                                      \
            U4 pa;                                                             \
            _Pragma("unroll")                                                  \
            for (int i = 0; i < 2; ++i) {                                      \
                i32x2 r = __builtin_amdgcn_permlane32_swap(                    \
                    (int)X[2][i], (int)X[3][i], false, false);                 \
                pa.u[i]     = (unsigned)r[0];                                  \
                pa.u[2 + i] = (unsigned)r[1];                                  \
            }                                                                  \
            accQ = __builtin_amdgcn_mfma_f32_32x32x16_f16(                     \
                pa.v, LDV(T, 1), accQ, 0, 0, 0);                               \
        }                                                                      \
        __builtin_amdgcn_s_setprio(0);                                         \
    }

    f32x16 scA = __builtin_amdgcn_mfma_f32_32x32x16_f16(LDK(0), qf, z16, 0, 0, 0);
    f32x16 scB = __builtin_amdgcn_mfma_f32_32x32x16_f16(LDK(1), qf, z16, 0, 0, 0);

#pragma unroll 4
    for (int kt = 0; kt < 62; kt += 2) {
        PROC(scA, kt,     kt + 2, 1)
        PROC(scB, kt + 1, kt + 3, 1)
    }
    PROC(scA, 62, 0, 0)                             // tails: no refill
    PROC(scB, 63, 0, 0)
#undef PROC
#undef LDK
#undef LDV

    f32x16 accO;
#pragma unroll
    for (int i = 0; i < 16; ++i) accO[i] = accP[i] + accQ[i];

    // ---- epilogue: normalize by col-8 (ones column) and store ----
    const int n = l31;
    float* obase = out + ((size_t)(b * S_ + qrow0)) * E_ + h * DK_ + n;
#pragma unroll
    for (int i = 0; i < 16; ++i) {
        float den = __shfl(accO[i], (lane & 32) | 8, 64);
        float val = accO[i] * frcp(den);
        int row = (i & 3) + 8 * (i >> 2) + 4 * hi;
        if (n < DK_) obase[(size_t)row * E_] = val;
    }
}

// ---------------------------------------------------------------------------
// In-place output projection via f16 MFMA:  io[r][:] = io[r][:] @ Wc^T + bc.
// 128 blocks x 64 rows. A (64x128) and Wc (128x128) staged as f16 in 48KB LDS
// with 16B-chunk XOR swizzle; wave w owns row-group w&1, col-groups
// {2*(w>>1), 2*(w>>1)+1}; 8 K-steps of 32x32x16 mfma.
// ---------------------------------------------------------------------------
__global__ __launch_bounds__(256, 2)
void proj_mfma(const float* __restrict__ Wc, const float* __restrict__ bc,
               float* __restrict__ io) {
    __shared__ __align__(16) _Float16 As[64 * E_];   // 16KB
    __shared__ __align__(16) _Float16 Bs[E_ * E_];   // 32KB
    const int tid  = threadIdx.x;
    const int lane = tid & 63;
    const int wv   = tid >> 6;
    const int l31  = lane & 31;
    const int hi   = lane >> 5;
    const int r0   = blockIdx.x * 64;

    // stage A rows (io, fp32 -> f16) with chunk swizzle
    for (int i = tid; i < 64 * 16; i += 256) {
        int r = i >> 4, c = i & 15;
        const float* s = io + (size_t)(r0 + r) * E_ + c * 8;
        float4 a = *(const float4*)s;
        float4 b = *(const float4*)(s + 4);
        H2U p0, p1, p2, p3;
        p0.h = __builtin_amdgcn_cvt_pkrtz(a.x, a.y);
        p1.h = __builtin_amdgcn_cvt_pkrtz(a.z, a.w);
        p2.h = __builtin_amdgcn_cvt_pkrtz(b.x, b.y);
        p3.h = __builtin_amdgcn_cvt_pkrtz(b.z, b.w);
        *(uint4*)&As[r * E_ + ((c ^ (r & 7)) * 8)] = make_uint4(p0.u, p1.u, p2.u, p3.u);
    }
    // stage Wc (fp32 -> f16) with chunk swizzle
    for (int i = tid; i < E_ * 16; i += 256) {
        int r = i >> 4, c = i & 15;
        const float* s = Wc + (size_t)r * E_ + c * 8;
        float4 a = *(const float4*)s;
        float4 b = *(const float4*)(s + 4);
        H2U p0, p1, p2, p3;
        p0.h = __builtin_amdgcn_cvt_pkrtz(a.x, a.y);
        p1.h = __builtin_amdgcn_cvt_pkrtz(a.z, a.w);
        p2.h = __builtin_amdgcn_cvt_pkrtz(b.x, b.y);
        p3.h = __builtin_amdgcn_cvt_pkrtz(b.z, b.w);
        *(uint4*)&Bs[r * E_ + ((c ^ (r & 7)) * 8)] = make_uint4(p0.u, p1.u, p2.u, p3.u);
    }
    __syncthreads();

    const int rg = wv & 1;                // row-group: rows rg*32 + m
    const int cp = (wv >> 1) * 2;         // col-groups cp, cp+1

    f32x16 acc0 = {}, acc1 = {};
#pragma unroll
    for (int ks = 0; ks < 8; ++ks) {
        int ch = (ks * 2 + hi);
        f16x8 af  = *(const f16x8*)&As[(rg * 32 + l31) * E_ + ((ch ^ (l31 & 7)) * 8)];
        f16x8 bf0 = *(const f16x8*)&Bs[((cp + 0) * 32 + l31) * E_ + ((ch ^ (l31 & 7)) * 8)];
        f16x8 bf1 = *(const f16x8*)&Bs[((cp + 1) * 32 + l31) * E_ + ((ch ^ (l31 & 7)) * 8)];
        acc0 = __builtin_amdgcn_mfma_f32_32x32x16_f16(af, bf0, acc0, 0, 0, 0);
        acc1 = __builtin_amdgcn_mfma_f32_32x32x16_f16(af, bf1, acc1, 0, 0, 0);
    }

    const float b0 = bc[(cp + 0) * 32 + l31];
    const float b1 = bc[(cp + 1) * 32 + l31];
#pragma unroll
    for (int i = 0; i < 16; ++i) {
        int row = (i & 3) + 8 * (i >> 2) + 4 * hi;
        float* orow = io + (size_t)(r0 + rg * 32 + row) * E_;
        orow[(cp + 0) * 32 + l31] = acc0[i] + b0;
        orow[(cp + 1) * 32 + l31] = acc1[i] + b1;
    }
}

extern "C" void kernel_launch(void* const* d_in, const int* in_sizes, int n_in,
                              void* d_out, int out_size, void* d_ws, size_t ws_size,
                              hipStream_t stream) {
    const float* x     = (const float*)d_in[0];   // (4, 2048, 128)
    const float* theta = (const float*)d_in[1];   // (8,)
    const float* Wc    = (const float*)d_in[2];   // (128, 128)
    const float* bc    = (const float*)d_in[3];   // (128,)
    float* out = (float*)d_out;                   // (4, 2048, 128)

    qattn_mfma<<<dim3(S_ / 256, B_ * H_), 512, 0, stream>>>(x, theta, out);
    proj_mfma<<<dim3((B_ * S_) / 64), 256, 0, stream>>>(Wc, bc, out);
}